// Round 2
// baseline (1188.966 us; speedup 1.0000x reference)
//
#include <hip/hip_runtime.h>
#include <math.h>

// ---- static config ----
constexpr int cB = 16, cL = 192, cCIN = 21, cD = 128;
constexpr int cP = 24, cNT = 16, cHW = 24;
constexpr int cPRED = 96, cCOUT = 21;
constexpr int cYH = 14, cYW = 22;           // valid-conv output of (16,24) with 3x3
constexpr int cYHW = cYH * cYW;             // 308

// K1: token conv (circular pad) + positional embedding -> emb (B, L, D)
__global__ void k_embed(const float* __restrict__ x, const float* __restrict__ tw,
                        float* __restrict__ emb) {
    int idx = blockIdx.x * blockDim.x + threadIdx.x;
    if (idx >= cB * cL * cD) return;
    int d = idx & 127;
    int bl = idx >> 7;
    int l = bl % cL;
    int b = bl / cL;
    float acc = 0.f;
    #pragma unroll
    for (int k = 0; k < 3; ++k) {
        int ll = l + k - 1;
        if (ll < 0) ll += cL;
        if (ll >= cL) ll -= cL;
        const float* xp = x + (b * cL + ll) * cCIN;   // x[b, ll, c]
        const float* wp = tw + d * cCIN * 3 + k;      // tw[d, c, k]
        for (int c = 0; c < cCIN; ++c) acc += xp[c] * wp[c * 3];
    }
    // pos embed: pe[l, 2i] = sin(l*div_i), pe[l, 2i+1] = cos(l*div_i)
    int i2 = d >> 1;
    float dv = expf(-(float)(2 * i2) * (9.210340371976184f / 128.f)); // ln(10000)/D
    float ang = (float)l * dv;
    float pe = (d & 1) ? cosf(ang) : sinf(ang);
    emb[idx] = acc + pe;
}

// K2: patch embedding (torch reshape semantics) -> x5 (B, D, NT, 2, 12)
__global__ void k_patch(const float* __restrict__ emb, const float* __restrict__ pw,
                        const float* __restrict__ pb, float* __restrict__ x5) {
    int idx = blockIdx.x * blockDim.x + threadIdx.x;
    if (idx >= cB * cD * cNT * cHW) return;
    // layout: ((b*128 + cc)*16 + t)*24 + h*12 + w
    int hw = idx % 24;
    int w = hw % 12;
    int h = hw / 12;
    int r = idx / 24;
    int t = r % 16;
    r /= 16;
    int cc = r & 127;
    int b = r >> 7;
    int ppatch = 2 * w + h;                    // patch-channel index after even/odd stack
    // xe[b, t, ppatch, cc] maps through flat F = b*49152 + t*3072 + ppatch*128 + cc
    // back to conv output xe2[i, tt, p] with F = i*384 + tt*24 + p
    int G = t * 3072 + ppatch * 128 + cc;      // < 49152
    int i = b * 128 + G / 384;
    int rem = G % 384;
    int tt = rem / 24;
    int p = rem % 24;
    const float* ebase = emb + i * 192;        // emb viewed as (2048, 192)
    float acc = pb[p];
    int j0 = tt * 12;
    #pragma unroll
    for (int k = 0; k < 24; ++k) {
        int j = j0 + k;
        if (j > 191) j = 191;                  // replicate pad (0, P-S)
        acc += ebase[j] * pw[p * 24 + k];
    }
    x5[idx] = acc;
}

// K3a: pp[b,c,t] = mean over (h,w)
__global__ void k_pool(const float* __restrict__ x5, float* __restrict__ pp) {
    int idx = blockIdx.x * blockDim.x + threadIdx.x;
    if (idx >= cB * cD * cNT) return;
    const float* p = x5 + idx * cHW;
    float s = 0.f;
    #pragma unroll
    for (int i = 0; i < cHW; ++i) s += p[i];
    pp[idx] = s * (1.f / 24.f);
}

// K3b: period conv (k=3, zero pad 1) + eval BN + relu -> ppr[b,o,t]
__global__ void k_pconv(const float* __restrict__ pp, const float* __restrict__ pw,
                        const float* __restrict__ pb, const float* __restrict__ g,
                        const float* __restrict__ bb, float* __restrict__ ppr) {
    int idx = blockIdx.x * blockDim.x + threadIdx.x;
    if (idx >= cB * cD * cNT) return;
    int t = idx % cNT;
    int r = idx / cNT;
    int o = r & 127;
    int b = r >> 7;
    float acc = pb[o];
    #pragma unroll
    for (int k = 0; k < 3; ++k) {
        int tt = t + k - 1;
        if (tt < 0 || tt >= cNT) continue;
        const float* pbase = pp + b * cD * cNT + tt;  // pp[b, c, tt]
        const float* wbase = pw + o * cD * 3 + k;     // pw[o, c, k]
        for (int c = 0; c < cD; ++c) acc += pbase[c * cNT] * wbase[c * 3];
    }
    float scale = g[o] * rsqrtf(1.f + 1e-5f);
    float v = acc * scale + bb[o];
    ppr[idx] = v > 0.f ? v : 0.f;
}

// K3c: pooled over t, then alpha[b,o] = aw@pooled + 1
__global__ void k_alpha(const float* __restrict__ ppr, const float* __restrict__ aw,
                        float* __restrict__ alpha) {
    int b = blockIdx.x;
    int o = threadIdx.x;
    __shared__ float pooled[cD];
    const float* base = ppr + (b * cD + o) * cNT;
    float s = 0.f;
    #pragma unroll
    for (int t = 0; t < cNT; ++t) s += base[t];
    pooled[o] = s * (1.f / 16.f);
    __syncthreads();
    float a = 1.f;
    for (int c = 0; c < cD; ++c) a += aw[o * cD + c] * pooled[c];
    alpha[b * cD + o] = a;
}

// K3d: s2[o] = sum_b alpha[b,o]^2
__global__ void k_s2(const float* __restrict__ alpha, float* __restrict__ s2) {
    int o = threadIdx.x;
    float s = 0.f;
    #pragma unroll
    for (int b = 0; b < cB; ++b) {
        float a = alpha[b * cD + o];
        s += a * a;
    }
    s2[o] = s;
}

// K4: Y0s[n,o,i,j] = s2[o] * conv2d_valid(x5, Wi)   (16,128,14,22)
__global__ void k_conv_fwd(const float* __restrict__ x5, const float* __restrict__ Wl,
                           const float* __restrict__ s2, float* __restrict__ y0) {
    int idx = blockIdx.x * blockDim.x + threadIdx.x;
    if (idx >= cB * cD * cYHW) return;
    int j = idx % cYW;
    int r = idx / cYW;
    int i = r % cYH;
    r /= cYH;
    int o = r & 127;
    int n = r >> 7;
    float acc = 0.f;
    const float* wb = Wl + o * cD * 9;
    const float* xb = x5 + n * (cD * cNT * cHW) + i * 24 + j;
    for (int c = 0; c < cD; ++c) {
        const float* xp = xb + c * 384;
        const float* wp = wb + c * 9;
        #pragma unroll
        for (int kh = 0; kh < 3; ++kh)
            #pragma unroll
            for (int kw = 0; kw < 3; ++kw)
                acc += xp[kh * 24 + kw] * wp[kh * 3 + kw];
    }
    y0[idx] = acc * s2[o];
}

// K5: x5 += conv_transpose(Y0s, Wi)  (full-correlation form, in-place residual)
__global__ void k_conv_bwd(float* __restrict__ x5, const float* __restrict__ y0,
                           const float* __restrict__ Wl) {
    int idx = blockIdx.x * blockDim.x + threadIdx.x;
    if (idx >= cB * cD * cNT * cHW) return;
    int j = idx % 24;
    int r = idx / 24;
    int i = r % 16;
    r /= 16;
    int c = r & 127;
    int n = r >> 7;
    float acc = x5[idx];
    const float* yn = y0 + n * cD * cYHW;
    for (int o = 0; o < cD; ++o) {
        const float* yp = yn + o * cYHW;
        const float* wp = Wl + (o * cD + c) * 9;
        #pragma unroll
        for (int a = 0; a < 3; ++a) {
            int yi = i - a;
            if (yi < 0 || yi >= cYH) continue;
            #pragma unroll
            for (int b2 = 0; b2 < 3; ++b2) {
                int yj = j - b2;
                if (yj < 0 || yj >= cYW) continue;
                acc += yp[yi * cYW + yj] * wp[a * 3 + b2];
            }
        }
    }
    x5[idx] = acc;
}

// K6: y1[b,d,p] = sum_m xf[b,m,d] * fc1_w[p,m] + fc1_b[p]
__global__ void k_fc1(const float* __restrict__ x5, const float* __restrict__ w,
                      const float* __restrict__ bias, float* __restrict__ y1) {
    int idx = blockIdx.x * blockDim.x + threadIdx.x;
    if (idx >= cB * cD * cPRED) return;
    int p = idx % cPRED;
    int r = idx / cPRED;
    int d = r & 127;
    int b = r >> 7;
    const float* xb = x5 + b * 49152 + d;   // xf[b,m,d] = x5flat[b*49152 + m*128 + d]
    const float* wb = w + p * 384;
    float acc = bias[p];
    for (int m = 0; m < 384; ++m) acc += xb[m * 128] * wb[m];
    y1[idx] = acc;  // layout (b, d, p)
}

// K7: out[b,p,q] = sum_d y1[b,d,p] * fc2_w[q,d] + fc2_b[q]
__global__ void k_fc2(const float* __restrict__ y1, const float* __restrict__ w,
                      const float* __restrict__ bias, float* __restrict__ out) {
    int idx = blockIdx.x * blockDim.x + threadIdx.x;
    if (idx >= cB * cPRED * cCOUT) return;
    int q = idx % cCOUT;
    int r = idx / cCOUT;
    int p = r % cPRED;
    int b = r / cPRED;
    const float* yb = y1 + b * cD * cPRED + p;
    const float* wb = w + q * cD;
    float acc = bias[q];
    for (int d = 0; d < cD; ++d) acc += yb[d * cPRED] * wb[d];
    out[idx] = acc;
}

extern "C" void kernel_launch(void* const* d_in, const int* in_sizes, int n_in,
                              void* d_out, int out_size, void* d_ws, size_t ws_size,
                              hipStream_t stream) {
    const float* x       = (const float*)d_in[0];
    const float* token_w = (const float*)d_in[1];
    const float* patch_w = (const float*)d_in[2];
    const float* patch_b = (const float*)d_in[3];
    const float* Wi      = (const float*)d_in[4];
    const float* pconv_w = (const float*)d_in[5];
    const float* pconv_b = (const float*)d_in[6];
    const float* bn_g    = (const float*)d_in[7];
    const float* bn_b    = (const float*)d_in[8];
    const float* aconv_w = (const float*)d_in[9];
    const float* fc1_w   = (const float*)d_in[10];
    const float* fc1_b   = (const float*)d_in[11];
    const float* fc2_w   = (const float*)d_in[12];
    const float* fc2_b   = (const float*)d_in[13];
    float* out = (float*)d_out;

    float* ws    = (float*)d_ws;
    float* emb   = ws;                 // 393216
    float* x5    = emb + 393216;       // 786432
    float* pp    = x5 + 786432;        // 32768
    float* ppr   = pp + 32768;         // 32768
    float* alpha = ppr + 32768;        // 2048
    float* s2    = alpha + 2048;       // 128
    float* y0    = s2 + 128;           // 630784
    float* y1    = y0 + 630784;        // 196608
    // total: 2,074,752 floats (~8.3 MB) — well under ws

    const int thr = 256;
    k_embed<<<(cB * cL * cD + thr - 1) / thr, thr, 0, stream>>>(x, token_w, emb);
    k_patch<<<(cB * cD * cNT * cHW + thr - 1) / thr, thr, 0, stream>>>(emb, patch_w, patch_b, x5);
    for (int l = 0; l < 2; ++l) {
        const float* Wl  = Wi + l * 147456;
        const float* pwl = pconv_w + l * 49152;
        const float* pbl = pconv_b + l * 128;
        const float* gl  = bn_g + l * 128;
        const float* bl  = bn_b + l * 128;
        const float* al  = aconv_w + l * 16384;
        k_pool<<<(cB * cD * cNT + thr - 1) / thr, thr, 0, stream>>>(x5, pp);
        k_pconv<<<(cB * cD * cNT + thr - 1) / thr, thr, 0, stream>>>(pp, pwl, pbl, gl, bl, ppr);
        k_alpha<<<cB, cD, 0, stream>>>(ppr, al, alpha);
        k_s2<<<1, cD, 0, stream>>>(alpha, s2);
        k_conv_fwd<<<(cB * cD * cYHW + thr - 1) / thr, thr, 0, stream>>>(x5, Wl, s2, y0);
        k_conv_bwd<<<(cB * cD * cNT * cHW + thr - 1) / thr, thr, 0, stream>>>(x5, y0, Wl);
    }
    k_fc1<<<(cB * cD * cPRED + thr - 1) / thr, thr, 0, stream>>>(x5, fc1_w, fc1_b, y1);
    k_fc2<<<(cB * cPRED * cCOUT + thr - 1) / thr, thr, 0, stream>>>(y1, fc2_w, fc2_b, out);
}

// Round 3
// 315.090 us; speedup vs baseline: 3.7734x; 3.7734x over previous
//
#include <hip/hip_runtime.h>
#include <math.h>

// ---- static config ----
constexpr int cB = 16, cL = 192, cCIN = 21, cD = 128;
constexpr int cNT = 16, cHW = 24;
constexpr int cPRED = 96, cCOUT = 21;
constexpr int cYH = 14, cYW = 22;

typedef __attribute__((ext_vector_type(8))) short bf16x8;   // 8 bf16 (4 VGPRs)
typedef __attribute__((ext_vector_type(4))) float f32x4;

__device__ inline unsigned short f2bf(float f) {
    union { float f; unsigned u; } v; v.f = f;
    unsigned u = v.u;
    unsigned r = (u + 0x7fffu + ((u >> 16) & 1u)) >> 16;
    return (unsigned short)r;
}

// ---------- K1: token conv (circular pad) + positional embedding ----------
__global__ void k_embed(const float* __restrict__ x, const float* __restrict__ tw,
                        float* __restrict__ emb) {
    int idx = blockIdx.x * blockDim.x + threadIdx.x;
    if (idx >= cB * cL * cD) return;
    int d = idx & 127;
    int bl = idx >> 7;
    int l = bl % cL;
    int b = bl / cL;
    float acc = 0.f;
    #pragma unroll
    for (int k = 0; k < 3; ++k) {
        int ll = l + k - 1;
        if (ll < 0) ll += cL;
        if (ll >= cL) ll -= cL;
        const float* xp = x + (b * cL + ll) * cCIN;
        const float* wp = tw + d * cCIN * 3 + k;
        for (int c = 0; c < cCIN; ++c) acc += xp[c] * wp[c * 3];
    }
    int i2 = d >> 1;
    float dv = expf(-(float)(2 * i2) * (9.210340371976184f / 128.f));
    float ang = (float)l * dv;
    float pe = (d & 1) ? cosf(ang) : sinf(ang);
    emb[idx] = acc + pe;
}

// ---------- K2: patch embedding (torch reshape semantics) -> x5 (B,D,16,24) ----------
__global__ void k_patch(const float* __restrict__ emb, const float* __restrict__ pw,
                        const float* __restrict__ pb, float* __restrict__ x5) {
    int idx = blockIdx.x * blockDim.x + threadIdx.x;
    if (idx >= cB * cD * cNT * cHW) return;
    int hw = idx % 24;
    int w = hw % 12;
    int h = hw / 12;
    int r = idx / 24;
    int t = r % 16;
    r /= 16;
    int cc = r & 127;
    int b = r >> 7;
    int ppatch = 2 * w + h;
    int G = t * 3072 + ppatch * 128 + cc;
    int i = b * 128 + G / 384;
    int rem = G % 384;
    int tt = rem / 24;
    int p = rem % 24;
    const float* ebase = emb + i * 192;
    float acc = pb[p];
    int j0 = tt * 12;
    #pragma unroll
    for (int k = 0; k < 24; ++k) {
        int j = j0 + k;
        if (j > 191) j = 191;
        acc += ebase[j] * pw[p * 24 + k];
    }
    x5[idx] = acc;
}

// ---------- small kernels (pool / pconv / alpha / s2) ----------
__global__ void k_pool(const float* __restrict__ x5, float* __restrict__ pp) {
    int idx = blockIdx.x * blockDim.x + threadIdx.x;
    if (idx >= cB * cD * cNT) return;
    const float* p = x5 + idx * cHW;
    float s = 0.f;
    #pragma unroll
    for (int i = 0; i < cHW; ++i) s += p[i];
    pp[idx] = s * (1.f / 24.f);
}

__global__ void k_pconv(const float* __restrict__ pp, const float* __restrict__ pw,
                        const float* __restrict__ pb, const float* __restrict__ g,
                        const float* __restrict__ bb, float* __restrict__ ppr) {
    int idx = blockIdx.x * blockDim.x + threadIdx.x;
    if (idx >= cB * cD * cNT) return;
    int t = idx % cNT;
    int r = idx / cNT;
    int o = r & 127;
    int b = r >> 7;
    float acc = pb[o];
    #pragma unroll
    for (int k = 0; k < 3; ++k) {
        int tt = t + k - 1;
        if (tt < 0 || tt >= cNT) continue;
        const float* pbase = pp + b * cD * cNT + tt;
        const float* wbase = pw + o * cD * 3 + k;
        for (int c = 0; c < cD; ++c) acc += pbase[c * cNT] * wbase[c * 3];
    }
    float scale = g[o] * rsqrtf(1.f + 1e-5f);
    float v = acc * scale + bb[o];
    ppr[idx] = v > 0.f ? v : 0.f;
}

__global__ void k_alpha(const float* __restrict__ ppr, const float* __restrict__ aw,
                        float* __restrict__ alpha) {
    int b = blockIdx.x;
    int o = threadIdx.x;
    __shared__ float pooled[cD];
    const float* base = ppr + (b * cD + o) * cNT;
    float s = 0.f;
    #pragma unroll
    for (int t = 0; t < cNT; ++t) s += base[t];
    pooled[o] = s * (1.f / 16.f);
    __syncthreads();
    float a = 1.f;
    for (int c = 0; c < cD; ++c) a += aw[o * cD + c] * pooled[c];
    alpha[b * cD + o] = a;
}

__global__ void k_s2(const float* __restrict__ alpha, float* __restrict__ s2) {
    int o = threadIdx.x;
    float s = 0.f;
    #pragma unroll
    for (int b = 0; b < cB; ++b) {
        float a = alpha[b * cD + o];
        s += a * a;
    }
    s2[o] = s;
}

// ---------- weight pack: Wp[lyr][dir][kt36][oi8][kg4][r16][j8] (bf16) ----------
// dir 0 (fwd GEMM B): k=(a,c): value = W[o=oi*16+r][c=k&127][a=k>>7]
// dir 1 (bwd GEMM B): k=(a,o): value = W[o=k&127][c=oi*16+r][a=k>>7]
__global__ void k_wpack(const float* __restrict__ Wi, unsigned short* __restrict__ Wp) {
    int e = blockIdx.x * blockDim.x + threadIdx.x;
    if (e >= 2 * 2 * 147456) return;
    int lyr = e / 294912;
    int rem = e % 294912;
    int dir = rem / 147456;
    int q = rem % 147456;
    int kt = q >> 12;
    int oi = (q >> 9) & 7;
    int kg = (q >> 7) & 3;
    int r  = (q >> 3) & 15;
    int j  = q & 7;
    int k = kt * 32 + kg * 8 + j;
    int a = k >> 7;
    int o, c;
    if (dir == 0) { o = oi * 16 + r; c = k & 127; }
    else          { o = k & 127;     c = oi * 16 + r; }
    float val = Wi[lyr * 147456 + o * 1152 + c * 9 + a];
    Wp[e] = f2bf(val);
}

// ---------- XT pack: XT[n][pp 448][c 128] bf16, pp>=384 zero ----------
__global__ void k_xtpack(const float* __restrict__ x5, unsigned short* __restrict__ XT) {
    __shared__ unsigned short tile[64][128];
    int blk = blockIdx.x;              // 112 = 16n * 7
    int n = blk / 7, pb = blk % 7;
    int pp0 = pb * 64;
    int t = threadIdx.x;
    if (pb < 6) {
        int p4 = (t & 15) * 4;
        #pragma unroll
        for (int i = 0; i < 8; ++i) {
            int c = (t >> 4) + i * 16;
            f32x4 v = *(const f32x4*)(x5 + n * 49152 + c * 384 + pp0 + p4);
            #pragma unroll
            for (int r = 0; r < 4; ++r) tile[p4 + r][c] = f2bf(v[r]);
        }
        __syncthreads();
        #pragma unroll
        for (int i = 0; i < 4; ++i) {
            int idx = t + i * 256;
            int pp = idx >> 4;
            int c8 = (idx & 15) * 8;
            *(bf16x8*)(XT + n * 57344 + (pp0 + pp) * 128 + c8) = *(bf16x8*)&tile[pp][c8];
        }
    } else {
        #pragma unroll
        for (int i = 0; i < 4; ++i) {
            int idx = t + i * 256;
            int pp = idx >> 4;
            int c8 = (idx & 15) * 8;
            bf16x8 z = {0, 0, 0, 0, 0, 0, 0, 0};
            *(bf16x8*)(XT + n * 57344 + (384 + pp) * 128 + c8) = z;
        }
    }
}

// ---------- zero Y0T (16*512*128 bf16) ----------
__global__ void k_zero(unsigned short* __restrict__ Y0T) {
    int idx = blockIdx.x * blockDim.x + threadIdx.x;
    if (idx >= 131072) return;
    bf16x8 z = {0, 0, 0, 0, 0, 0, 0, 0};
    *(bf16x8*)(Y0T + idx * 8) = z;
}

// ---------- GEMM fwd: Y0T[n][64+p][o] = mask(p) * s2[o] * sum_k XT[n][p+off][c]*W ----------
__global__ __launch_bounds__(256) void k_gemm_fwd(const unsigned short* __restrict__ XT,
                                                  const unsigned short* __restrict__ Wp,
                                                  const float* __restrict__ s2,
                                                  unsigned short* __restrict__ Y0T) {
    __shared__ unsigned short Atile[2048];   // [mi4][kg4][m16][j8]
    __shared__ unsigned short Btile[2048];   // [ni4][kg4][o16][j8]
    int bid = blockIdx.x;                    // 192
    int N0 = (bid & 1) << 6;
    int wgM = bid >> 1;                      // 0..95
    int n = wgM / 6;
    int p0 = (wgM % 6) << 6;
    int t = threadIdx.x;
    int l = t & 63, w = t >> 6;
    int wm = w >> 1, wn = w & 1;
    const unsigned short* XTn = XT + n * 57344;
    f32x4 acc[2][2];
    #pragma unroll
    for (int i = 0; i < 2; ++i)
        #pragma unroll
        for (int j = 0; j < 2; ++j) acc[i][j] = (f32x4){0.f, 0.f, 0.f, 0.f};
    int sm = l & 15;
    int skg = l >> 4;
    for (int kt = 0; kt < 36; ++kt) {
        int a = kt >> 2;
        int off = (a / 3) * 24 + (a % 3);
        int c0 = (kt & 3) << 5;
        bf16x8 av = *(const bf16x8*)(XTn + (p0 + w * 16 + sm + off) * 128 + c0 + skg * 8);
        bf16x8 bv = *(const bf16x8*)(Wp + kt * 4096 + ((N0 >> 4) + w) * 512 + l * 8);
        __syncthreads();
        *(bf16x8*)(Atile + t * 8) = av;
        *(bf16x8*)(Btile + t * 8) = bv;
        __syncthreads();
        bf16x8 a0 = *(const bf16x8*)(Atile + (wm * 2 + 0) * 512 + l * 8);
        bf16x8 a1 = *(const bf16x8*)(Atile + (wm * 2 + 1) * 512 + l * 8);
        bf16x8 b0 = *(const bf16x8*)(Btile + (wn * 2 + 0) * 512 + l * 8);
        bf16x8 b1 = *(const bf16x8*)(Btile + (wn * 2 + 1) * 512 + l * 8);
        acc[0][0] = __builtin_amdgcn_mfma_f32_16x16x32_bf16(a0, b0, acc[0][0], 0, 0, 0);
        acc[0][1] = __builtin_amdgcn_mfma_f32_16x16x32_bf16(a0, b1, acc[0][1], 0, 0, 0);
        acc[1][0] = __builtin_amdgcn_mfma_f32_16x16x32_bf16(a1, b0, acc[1][0], 0, 0, 0);
        acc[1][1] = __builtin_amdgcn_mfma_f32_16x16x32_bf16(a1, b1, acc[1][1], 0, 0, 0);
    }
    #pragma unroll
    for (int mi = 0; mi < 2; ++mi)
        #pragma unroll
        for (int ni = 0; ni < 2; ++ni) {
            int o = N0 + wn * 32 + ni * 16 + (l & 15);
            float s = s2[o];
            #pragma unroll
            for (int r = 0; r < 4; ++r) {
                int p = p0 + wm * 32 + mi * 16 + ((l >> 4) << 2) + r;
                bool valid = ((p % 24) < cYW) && ((p / 24) < cYH);
                float v = valid ? acc[mi][ni][r] * s : 0.f;
                Y0T[n * 65536 + (64 + p) * 128 + o] = f2bf(v);
            }
        }
}

// ---------- GEMM bwd: x5[n][c][p] += sum_{a,o} Y0T[n][64+p-off][o] * W[o][c][a] ----------
__global__ __launch_bounds__(256) void k_gemm_bwd(const unsigned short* __restrict__ Y0T,
                                                  const unsigned short* __restrict__ Wp,
                                                  float* __restrict__ x5) {
    __shared__ unsigned short Atile[2048];
    __shared__ unsigned short Btile[2048];
    int bid = blockIdx.x;
    int N0 = (bid & 1) << 6;
    int wgM = bid >> 1;
    int n = wgM / 6;
    int p0 = (wgM % 6) << 6;
    int t = threadIdx.x;
    int l = t & 63, w = t >> 6;
    int wm = w >> 1, wn = w & 1;
    const unsigned short* Yn = Y0T + n * 65536;
    f32x4 acc[2][2];
    #pragma unroll
    for (int i = 0; i < 2; ++i)
        #pragma unroll
        for (int j = 0; j < 2; ++j) acc[i][j] = (f32x4){0.f, 0.f, 0.f, 0.f};
    int sm = l & 15;
    int skg = l >> 4;
    for (int kt = 0; kt < 36; ++kt) {
        int a = kt >> 2;
        int off = (a / 3) * 24 + (a % 3);
        int o0 = (kt & 3) << 5;
        bf16x8 av = *(const bf16x8*)(Yn + (64 + p0 + w * 16 + sm - off) * 128 + o0 + skg * 8);
        bf16x8 bv = *(const bf16x8*)(Wp + kt * 4096 + ((N0 >> 4) + w) * 512 + l * 8);
        __syncthreads();
        *(bf16x8*)(Atile + t * 8) = av;
        *(bf16x8*)(Btile + t * 8) = bv;
        __syncthreads();
        bf16x8 a0 = *(const bf16x8*)(Atile + (wm * 2 + 0) * 512 + l * 8);
        bf16x8 a1 = *(const bf16x8*)(Atile + (wm * 2 + 1) * 512 + l * 8);
        bf16x8 b0 = *(const bf16x8*)(Btile + (wn * 2 + 0) * 512 + l * 8);
        bf16x8 b1 = *(const bf16x8*)(Btile + (wn * 2 + 1) * 512 + l * 8);
        acc[0][0] = __builtin_amdgcn_mfma_f32_16x16x32_bf16(a0, b0, acc[0][0], 0, 0, 0);
        acc[0][1] = __builtin_amdgcn_mfma_f32_16x16x32_bf16(a0, b1, acc[0][1], 0, 0, 0);
        acc[1][0] = __builtin_amdgcn_mfma_f32_16x16x32_bf16(a1, b0, acc[1][0], 0, 0, 0);
        acc[1][1] = __builtin_amdgcn_mfma_f32_16x16x32_bf16(a1, b1, acc[1][1], 0, 0, 0);
    }
    #pragma unroll
    for (int mi = 0; mi < 2; ++mi)
        #pragma unroll
        for (int ni = 0; ni < 2; ++ni) {
            int c = N0 + wn * 32 + ni * 16 + (l & 15);
            int p = p0 + wm * 32 + mi * 16 + ((l >> 4) << 2);
            float* dst = x5 + n * 49152 + c * 384 + p;
            f32x4 ov = *(f32x4*)dst;
            #pragma unroll
            for (int r = 0; r < 4; ++r) ov[r] += acc[mi][ni][r];
            *(f32x4*)dst = ov;
        }
}

// ---------- heads ----------
__global__ void k_fc1(const float* __restrict__ x5, const float* __restrict__ w,
                      const float* __restrict__ bias, float* __restrict__ y1) {
    int idx = blockIdx.x * blockDim.x + threadIdx.x;
    if (idx >= cB * cD * cPRED) return;
    int p = idx % cPRED;
    int r = idx / cPRED;
    int d = r & 127;
    int b = r >> 7;
    const float* xb = x5 + b * 49152 + d;
    const float* wb = w + p * 384;
    float acc = bias[p];
    for (int m = 0; m < 384; ++m) acc += xb[m * 128] * wb[m];
    y1[idx] = acc;
}

__global__ void k_fc2(const float* __restrict__ y1, const float* __restrict__ w,
                      const float* __restrict__ bias, float* __restrict__ out) {
    int idx = blockIdx.x * blockDim.x + threadIdx.x;
    if (idx >= cB * cPRED * cCOUT) return;
    int q = idx % cCOUT;
    int r = idx / cCOUT;
    int p = r % cPRED;
    int b = r / cPRED;
    const float* yb = y1 + b * cD * cPRED + p;
    const float* wb = w + q * cD;
    float acc = bias[q];
    for (int d = 0; d < cD; ++d) acc += yb[d * cPRED] * wb[d];
    out[idx] = acc;
}

extern "C" void kernel_launch(void* const* d_in, const int* in_sizes, int n_in,
                              void* d_out, int out_size, void* d_ws, size_t ws_size,
                              hipStream_t stream) {
    const float* x       = (const float*)d_in[0];
    const float* token_w = (const float*)d_in[1];
    const float* patch_w = (const float*)d_in[2];
    const float* patch_b = (const float*)d_in[3];
    const float* Wi      = (const float*)d_in[4];
    const float* pconv_w = (const float*)d_in[5];
    const float* pconv_b = (const float*)d_in[6];
    const float* bn_g    = (const float*)d_in[7];
    const float* bn_b    = (const float*)d_in[8];
    const float* aconv_w = (const float*)d_in[9];
    const float* fc1_w   = (const float*)d_in[10];
    const float* fc1_b   = (const float*)d_in[11];
    const float* fc2_w   = (const float*)d_in[12];
    const float* fc2_b   = (const float*)d_in[13];
    float* out = (float*)d_out;

    // ---- workspace layout (floats) ----
    float* ws    = (float*)d_ws;
    float* x5    = ws;                         // 786432
    float* pp    = ws + 786432;                // 32768
    float* ppr   = ws + 819200;                // 32768
    float* alpha = ws + 851968;                // 2048
    float* s2    = ws + 854016;                // 128
    unsigned short* Wp = (unsigned short*)(ws + 854144);   // 589824 ush = 294912 f
    float* emb   = ws + 1149056;               // 393216 f (dead after k_patch)
    unsigned short* XT = (unsigned short*)(ws + 1149056);  // 917504 ush (aliases emb)
    unsigned short* Y0T = (unsigned short*)(ws + 1607808); // 1048576 ush
    float* y1    = ws + 1607808;               // 196608 f (aliases Y0T, used after)
    // total: 2,132,096 floats = 8.53 MB

    const int thr = 256;
    k_wpack<<<2304, thr, 0, stream>>>(Wi, Wp);
    k_embed<<<1536, thr, 0, stream>>>(x, token_w, emb);
    k_patch<<<3072, thr, 0, stream>>>(emb, patch_w, patch_b, x5);
    for (int l = 0; l < 2; ++l) {
        const float* pwl = pconv_w + l * 49152;
        const float* pbl = pconv_b + l * 128;
        const float* gl  = bn_g + l * 128;
        const float* bl  = bn_b + l * 128;
        const float* al  = aconv_w + l * 16384;
        const unsigned short* Wpf = Wp + (l * 2 + 0) * 147456;
        const unsigned short* Wpb = Wp + (l * 2 + 1) * 147456;
        k_pool<<<128, thr, 0, stream>>>(x5, pp);
        k_pconv<<<128, thr, 0, stream>>>(pp, pwl, pbl, gl, bl, ppr);
        k_alpha<<<cB, cD, 0, stream>>>(ppr, al, alpha);
        k_s2<<<1, cD, 0, stream>>>(alpha, s2);
        k_xtpack<<<112, thr, 0, stream>>>(x5, XT);
        k_zero<<<512, thr, 0, stream>>>(Y0T);
        k_gemm_fwd<<<192, thr, 0, stream>>>(XT, Wpf, s2, Y0T);
        k_gemm_bwd<<<192, thr, 0, stream>>>(Y0T, Wpb, x5);
    }
    k_fc1<<<768, thr, 0, stream>>>(x5, fc1_w, fc1_b, y1);
    k_fc2<<<126, thr, 0, stream>>>(y1, fc2_w, fc2_b, out);
}

// Round 4
// 292.600 us; speedup vs baseline: 4.0634x; 1.0769x over previous
//
#include <hip/hip_runtime.h>
#include <math.h>

// ---- static config ----
constexpr int cB = 16, cL = 192, cCIN = 21, cD = 128;
constexpr int cNT = 16, cHW = 24;
constexpr int cPRED = 96, cCOUT = 21;
constexpr int cYH = 14, cYW = 22;

typedef __attribute__((ext_vector_type(8))) short bf16x8;
typedef __attribute__((ext_vector_type(4))) float f32x4;

__device__ inline unsigned short f2bf(float f) {
    union { float f; unsigned u; } v; v.f = f;
    unsigned u = v.u;
    unsigned r = (u + 0x7fffu + ((u >> 16) & 1u)) >> 16;
    return (unsigned short)r;
}

// ---------- pack: Wp (4x147456 frag-order), w1p (96x384 k-permuted), twT (63x128) ----------
__global__ void k_wpack(const float* __restrict__ Wi, const float* __restrict__ fc1_w,
                        const float* __restrict__ token_w,
                        unsigned short* __restrict__ Wp, unsigned short* __restrict__ w1p,
                        float* __restrict__ twT) {
    int e = blockIdx.x * blockDim.x + threadIdx.x;
    if (e < 589824) {
        int lyr = e / 294912;
        int rem = e % 294912;
        int dir = rem / 147456;
        int q = rem % 147456;
        int kt = q >> 12;
        int oi = (q >> 9) & 7;
        int kg = (q >> 7) & 3;
        int r  = (q >> 3) & 15;
        int j  = q & 7;
        int k = kt * 32 + kg * 8 + j;
        int a = k >> 7;
        int o, c;
        if (dir == 0) { o = oi * 16 + r; c = k & 127; }
        else          { o = k & 127;     c = oi * 16 + r; }
        Wp[e] = f2bf(Wi[lyr * 147456 + o * 1152 + c * 9 + a]);
    } else if (e < 589824 + 36864) {
        int e2 = e - 589824;
        int p = e2 / 384, mh = e2 % 384;
        // k-permutation: m = 3*(mh&127) + (mh>>7)
        w1p[e2] = f2bf(fc1_w[p * 384 + 3 * (mh & 127) + (mh >> 7)]);
    } else if (e < 589824 + 36864 + 8064) {
        int e3 = e - 589824 - 36864;
        int d = e3 & 127, c3 = e3 >> 7;   // c3 = c*3+kk
        twT[e3] = token_w[d * 63 + c3];
    }
}

// ---------- one-time Y0T halo zero (rows 0..63 and 448..511 per n) ----------
__global__ void k_zero_halo(unsigned short* __restrict__ Y0T) {
    int idx = blockIdx.x * blockDim.x + threadIdx.x;  // 32768
    int n = idx >> 11;
    int r = (idx >> 4) & 127;
    int c8 = idx & 15;
    int row = r < 64 ? r : r + 384;
    bf16x8 z = {0, 0, 0, 0, 0, 0, 0, 0};
    *(bf16x8*)(Y0T + n * 65536 + row * 128 + c8 * 8) = z;
}

// ---------- K1: token conv (circular) + pos embed, coalesced twT ----------
__global__ void k_embed(const float* __restrict__ x, const float* __restrict__ twT,
                        float* __restrict__ emb) {
    int idx = blockIdx.x * blockDim.x + threadIdx.x;
    if (idx >= cB * cL * cD) return;
    int d = idx & 127;
    int r = idx >> 7;
    int l = r % cL;
    int b = r / cL;
    int lm = (l == 0) ? 191 : l - 1;
    int lp = (l == 191) ? 0 : l + 1;
    const float* xb = x + b * 4032;
    float acc = 0.f;
    for (int c = 0; c < cCIN; ++c) {
        float x0 = xb[lm * 21 + c], x1 = xb[l * 21 + c], x2 = xb[lp * 21 + c];
        const float* tb = twT + c * 384 + d;   // (c*3+kk)*128 + d
        acc += x0 * tb[0] + x1 * tb[128] + x2 * tb[256];
    }
    int i2 = d >> 1;
    float dv = expf(-(float)(2 * i2) * (9.210340371976184f / 128.f));
    float ang = (float)l * dv;
    float pe = (d & 1) ? cosf(ang) : sinf(ang);
    emb[idx] = acc + pe;
}

// ---------- K2: patch embed, broadcast-read / scatter-write ----------
__global__ __launch_bounds__(192) void k_patch(const float* __restrict__ emb,
                                               const float* __restrict__ pw,
                                               const float* __restrict__ pb,
                                               float* __restrict__ x5) {
    __shared__ float pwL[24][24];
    int t = threadIdx.x;
    for (int z = t; z < 576; z += 192) pwL[z / 24][z % 24] = pw[z];
    __syncthreads();
    int pair = blockIdx.x * 8 + t / 24;   // (i,tt) pair, 0..32767
    int p = t % 24;
    int i = pair >> 4, tt = pair & 15;
    const float* ebase = emb + i * 192;
    int j0 = tt * 12;
    float acc = pb[p];
    #pragma unroll
    for (int k = 0; k < 24; ++k) {
        int j = j0 + k;
        j = j > 191 ? 191 : j;
        acc += ebase[j] * pwL[p][k];
    }
    int G = (i & 127) * 384 + tt * 24 + p;
    int b = i >> 7;
    int tp = G / 3072;
    int pp2 = (G % 3072) / 128;
    int cc = G & 127;
    int h = pp2 & 1, w2 = pp2 >> 1;
    x5[b * 49152 + cc * 384 + tp * 24 + h * 12 + w2] = acc;
}

// ---------- fused stats: pool + pconv + BN/relu + tpool + alpha (per b) ----------
__global__ __launch_bounds__(256) void k_stats(const float* __restrict__ x5,
        const float* __restrict__ pw, const float* __restrict__ pb,
        const float* __restrict__ g, const float* __restrict__ bb,
        const float* __restrict__ aw, float* __restrict__ alpha) {
    __shared__ float ppT[18][128];   // [1+t][c], rows 0,17 = zero pad
    __shared__ float part[256];
    __shared__ float pooled[128];
    int b = blockIdx.x, t = threadIdx.x;
    if (t < 128) { ppT[0][t] = 0.f; ppT[17][t] = 0.f; }
    #pragma unroll
    for (int i = 0; i < 8; ++i) {
        int ct = t + 256 * i;                 // c*16 + tt
        const float* p = x5 + b * 49152 + ct * 24;
        float s = 0.f;
        #pragma unroll
        for (int j = 0; j < 6; ++j) {
            f32x4 v = *(const f32x4*)(p + 4 * j);
            s += v[0] + v[1] + v[2] + v[3];
        }
        ppT[1 + (ct & 15)][ct >> 4] = s * (1.f / 24.f);
    }
    __syncthreads();
    int o = t >> 1, th = (t & 1) * 8;
    float acc[8];
    float pbo = pb[o];
    #pragma unroll
    for (int i = 0; i < 8; ++i) acc[i] = pbo;
    for (int c4 = 0; c4 < 32; ++c4) {
        union { f32x4 v[3]; float f[12]; } u;
        u.v[0] = *(const f32x4*)(pw + o * 384 + c4 * 12);
        u.v[1] = *(const f32x4*)(pw + o * 384 + c4 * 12 + 4);
        u.v[2] = *(const f32x4*)(pw + o * 384 + c4 * 12 + 8);
        f32x4 pv[10];
        #pragma unroll
        for (int r = 0; r < 10; ++r) pv[r] = *(f32x4*)&ppT[th + r][c4 * 4];
        #pragma unroll
        for (int cc = 0; cc < 4; ++cc) {
            float a0 = u.f[cc * 3], a1 = u.f[cc * 3 + 1], a2 = u.f[cc * 3 + 2];
            #pragma unroll
            for (int i = 0; i < 8; ++i)
                acc[i] += a0 * pv[i][cc] + a1 * pv[i + 1][cc] + a2 * pv[i + 2][cc];
        }
    }
    float scale = g[o] * rsqrtf(1.f + 1e-5f);
    float beta = bb[o];
    float partial = 0.f;
    #pragma unroll
    for (int i = 0; i < 8; ++i) {
        float v = acc[i] * scale + beta;
        partial += v > 0.f ? v : 0.f;
    }
    part[t] = partial;
    __syncthreads();
    if (t < 128) pooled[t] = (part[2 * t] + part[2 * t + 1]) * (1.f / 16.f);
    __syncthreads();
    if (t < 128) {
        float a = 1.f;
        for (int c4 = 0; c4 < 32; ++c4) {
            f32x4 av = *(const f32x4*)(aw + t * 128 + c4 * 4);
            f32x4 pv4 = *(f32x4*)&pooled[c4 * 4];
            a += av[0] * pv4[0] + av[1] * pv4[1] + av[2] * pv4[2] + av[3] * pv4[3];
        }
        alpha[b * 128 + t] = a;
    }
}

// ---------- XT pack (layer 0 only): XT[n][pp 448][c 128] bf16, pp>=384 zero ----------
__global__ void k_xtpack(const float* __restrict__ x5, unsigned short* __restrict__ XT) {
    __shared__ unsigned short tile[64][128];
    int blk = blockIdx.x;              // 112 = 16n * 7
    int n = blk / 7, pb = blk % 7;
    int pp0 = pb * 64;
    int t = threadIdx.x;
    if (pb < 6) {
        int p4 = (t & 15) * 4;
        #pragma unroll
        for (int i = 0; i < 8; ++i) {
            int c = (t >> 4) + i * 16;
            f32x4 v = *(const f32x4*)(x5 + n * 49152 + c * 384 + pp0 + p4);
            #pragma unroll
            for (int r = 0; r < 4; ++r) tile[p4 + r][c] = f2bf(v[r]);
        }
        __syncthreads();
        #pragma unroll
        for (int i = 0; i < 4; ++i) {
            int idx = t + i * 256;
            int pp = idx >> 4;
            int c8 = (idx & 15) * 8;
            *(bf16x8*)(XT + n * 57344 + (pp0 + pp) * 128 + c8) = *(bf16x8*)&tile[pp][c8];
        }
    } else {
        #pragma unroll
        for (int i = 0; i < 4; ++i) {
            int idx = t + i * 256;
            int pp = idx >> 4;
            int c8 = (idx & 15) * 8;
            bf16x8 z = {0, 0, 0, 0, 0, 0, 0, 0};
            *(bf16x8*)(XT + n * 57344 + (384 + pp) * 128 + c8) = z;
        }
    }
}

// ---------- GEMM fwd (+inline s2): Y0T[n][64+p][o] = mask*s2[o]*conv ----------
__global__ __launch_bounds__(256) void k_gemm_fwd(const unsigned short* __restrict__ XT,
                                                  const unsigned short* __restrict__ Wp,
                                                  const float* __restrict__ alpha,
                                                  unsigned short* __restrict__ Y0T) {
    __shared__ unsigned short Atile[2048];
    __shared__ unsigned short Btile[2048];
    __shared__ float partL[256];
    __shared__ float s2L[128];
    int t = threadIdx.x;
    float pa = 0.f;
    #pragma unroll
    for (int i = 0; i < 8; ++i) {
        float a = alpha[t + 256 * i];
        pa += a * a;
    }
    partL[t] = pa;
    int bid = blockIdx.x;
    int N0 = (bid & 1) << 6;
    int wgM = bid >> 1;
    int n = wgM / 6;
    int p0 = (wgM % 6) << 6;
    int l = t & 63, w = t >> 6;
    int wm = w >> 1, wn = w & 1;
    const unsigned short* XTn = XT + n * 57344;
    f32x4 acc[2][2];
    #pragma unroll
    for (int i = 0; i < 2; ++i)
        #pragma unroll
        for (int j = 0; j < 2; ++j) acc[i][j] = (f32x4){0.f, 0.f, 0.f, 0.f};
    int sm = l & 15;
    int skg = l >> 4;
    __syncthreads();
    if (t < 128) s2L[t] = partL[t] + partL[t + 128];
    for (int kt = 0; kt < 36; ++kt) {
        int a = kt >> 2;
        int off = (a / 3) * 24 + (a % 3);
        int c0 = (kt & 3) << 5;
        bf16x8 av = *(const bf16x8*)(XTn + (p0 + w * 16 + sm + off) * 128 + c0 + skg * 8);
        bf16x8 bv = *(const bf16x8*)(Wp + kt * 4096 + ((N0 >> 4) + w) * 512 + l * 8);
        __syncthreads();
        *(bf16x8*)(Atile + t * 8) = av;
        *(bf16x8*)(Btile + t * 8) = bv;
        __syncthreads();
        bf16x8 a0 = *(const bf16x8*)(Atile + (wm * 2 + 0) * 512 + l * 8);
        bf16x8 a1 = *(const bf16x8*)(Atile + (wm * 2 + 1) * 512 + l * 8);
        bf16x8 b0 = *(const bf16x8*)(Btile + (wn * 2 + 0) * 512 + l * 8);
        bf16x8 b1 = *(const bf16x8*)(Btile + (wn * 2 + 1) * 512 + l * 8);
        acc[0][0] = __builtin_amdgcn_mfma_f32_16x16x32_bf16(a0, b0, acc[0][0], 0, 0, 0);
        acc[0][1] = __builtin_amdgcn_mfma_f32_16x16x32_bf16(a0, b1, acc[0][1], 0, 0, 0);
        acc[1][0] = __builtin_amdgcn_mfma_f32_16x16x32_bf16(a1, b0, acc[1][0], 0, 0, 0);
        acc[1][1] = __builtin_amdgcn_mfma_f32_16x16x32_bf16(a1, b1, acc[1][1], 0, 0, 0);
    }
    #pragma unroll
    for (int mi = 0; mi < 2; ++mi)
        #pragma unroll
        for (int ni = 0; ni < 2; ++ni) {
            int o = N0 + wn * 32 + ni * 16 + (l & 15);
            float s = s2L[o];
            #pragma unroll
            for (int r = 0; r < 4; ++r) {
                int p = p0 + wm * 32 + mi * 16 + ((l >> 4) << 2) + r;
                bool valid = ((p % 24) < cYW) && ((p / 24) < cYH);
                float v = valid ? acc[mi][ni][r] * s : 0.f;
                Y0T[n * 65536 + (64 + p) * 128 + o] = f2bf(v);
            }
        }
}

// ---------- GEMM bwd: x5 += convT; epilogue also emits bf16 XT (mode 0) or xfT (mode 1) ----------
__global__ __launch_bounds__(256) void k_gemm_bwd(const unsigned short* __restrict__ Y0T,
                                                  const unsigned short* __restrict__ Wp,
                                                  float* __restrict__ x5,
                                                  unsigned short* __restrict__ xdst,
                                                  int mode) {
    __shared__ unsigned short Atile[2048];
    __shared__ unsigned short Btile[2048];
    __shared__ unsigned short tr[64][72];
    int bid = blockIdx.x;
    int N0 = (bid & 1) << 6;
    int wgM = bid >> 1;
    int n = wgM / 6;
    int p0 = (wgM % 6) << 6;
    int t = threadIdx.x;
    int l = t & 63, w = t >> 6;
    int wm = w >> 1, wn = w & 1;
    const unsigned short* Yn = Y0T + n * 65536;
    f32x4 acc[2][2];
    #pragma unroll
    for (int i = 0; i < 2; ++i)
        #pragma unroll
        for (int j = 0; j < 2; ++j) acc[i][j] = (f32x4){0.f, 0.f, 0.f, 0.f};
    int sm = l & 15;
    int skg = l >> 4;
    for (int kt = 0; kt < 36; ++kt) {
        int a = kt >> 2;
        int off = (a / 3) * 24 + (a % 3);
        int o0 = (kt & 3) << 5;
        bf16x8 av = *(const bf16x8*)(Yn + (64 + p0 + w * 16 + sm - off) * 128 + o0 + skg * 8);
        bf16x8 bv = *(const bf16x8*)(Wp + kt * 4096 + ((N0 >> 4) + w) * 512 + l * 8);
        __syncthreads();
        *(bf16x8*)(Atile + t * 8) = av;
        *(bf16x8*)(Btile + t * 8) = bv;
        __syncthreads();
        bf16x8 a0 = *(const bf16x8*)(Atile + (wm * 2 + 0) * 512 + l * 8);
        bf16x8 a1 = *(const bf16x8*)(Atile + (wm * 2 + 1) * 512 + l * 8);
        bf16x8 b0 = *(const bf16x8*)(Btile + (wn * 2 + 0) * 512 + l * 8);
        bf16x8 b1 = *(const bf16x8*)(Btile + (wn * 2 + 1) * 512 + l * 8);
        acc[0][0] = __builtin_amdgcn_mfma_f32_16x16x32_bf16(a0, b0, acc[0][0], 0, 0, 0);
        acc[0][1] = __builtin_amdgcn_mfma_f32_16x16x32_bf16(a0, b1, acc[0][1], 0, 0, 0);
        acc[1][0] = __builtin_amdgcn_mfma_f32_16x16x32_bf16(a1, b0, acc[1][0], 0, 0, 0);
        acc[1][1] = __builtin_amdgcn_mfma_f32_16x16x32_bf16(a1, b1, acc[1][1], 0, 0, 0);
    }
    #pragma unroll
    for (int mi = 0; mi < 2; ++mi)
        #pragma unroll
        for (int ni = 0; ni < 2; ++ni) {
            int cl = wn * 32 + ni * 16 + (l & 15);
            int pl = wm * 32 + mi * 16 + ((l >> 4) << 2);
            int c = N0 + cl;
            int p = p0 + pl;
            float* dst = x5 + n * 49152 + c * 384 + p;
            f32x4 ov = *(f32x4*)dst;
            #pragma unroll
            for (int r = 0; r < 4; ++r) {
                ov[r] += acc[mi][ni][r];
                tr[pl + r][cl] = f2bf(ov[r]);
            }
            *(f32x4*)dst = ov;
        }
    __syncthreads();
    #pragma unroll
    for (int i = 0; i < 2; ++i) {
        int run = t + i * 256;
        int pp = run >> 3;
        int c8 = (run & 7) * 8;
        bf16x8 v = *(bf16x8*)&tr[pp][c8];
        if (mode == 0) {
            // XT[n][p0+pp][N0+c8..]
            *(bf16x8*)(xdst + n * 57344 + (p0 + pp) * 128 + N0 + c8) = v;
        } else {
            // xfT[n][d = (p0&127)+pp][mh = (p0>>7)*128 + N0 + c8..]
            *(bf16x8*)(xdst + n * 49152 + ((p0 & 127) + pp) * 384 + (p0 >> 7) * 128 + N0 + c8) = v;
        }
    }
}

// ---------- fused head: GEMM1 (MFMA, 96x128 K=384) + GEMM2 (VALU, K=128) ----------
__global__ __launch_bounds__(256) void k_head(const unsigned short* __restrict__ xfT,
                                              const unsigned short* __restrict__ w1p,
                                              const float* __restrict__ b1,
                                              const float* __restrict__ w2,
                                              const float* __restrict__ b2,
                                              float* __restrict__ out) {
    __shared__ unsigned short Bs[128][40];
    __shared__ float C1[96][132];
    int b = blockIdx.x;
    int t = threadIdx.x;
    int l = t & 63, w = t >> 6;
    const unsigned short* xb = xfT + b * 49152;
    f32x4 acc[6][2];
    #pragma unroll
    for (int pi = 0; pi < 6; ++pi)
        #pragma unroll
        for (int ni = 0; ni < 2; ++ni) acc[pi][ni] = (f32x4){0.f, 0.f, 0.f, 0.f};
    for (int kt = 0; kt < 12; ++kt) {
        int k0 = kt * 32;
        __syncthreads();
        #pragma unroll
        for (int i = 0; i < 2; ++i) {
            int run = t + i * 256;
            int d = run >> 2, j8 = (run & 3) * 8;
            *(bf16x8*)&Bs[d][j8] = *(const bf16x8*)(xb + d * 384 + k0 + j8);
        }
        __syncthreads();
        bf16x8 bf0 = *(bf16x8*)&Bs[w * 32 + (l & 15)][(l >> 4) * 8];
        bf16x8 bf1 = *(bf16x8*)&Bs[w * 32 + 16 + (l & 15)][(l >> 4) * 8];
        #pragma unroll
        for (int pi = 0; pi < 6; ++pi) {
            bf16x8 af = *(const bf16x8*)(w1p + (pi * 16 + (l & 15)) * 384 + k0 + (l >> 4) * 8);
            acc[pi][0] = __builtin_amdgcn_mfma_f32_16x16x32_bf16(af, bf0, acc[pi][0], 0, 0, 0);
            acc[pi][1] = __builtin_amdgcn_mfma_f32_16x16x32_bf16(af, bf1, acc[pi][1], 0, 0, 0);
        }
    }
    __syncthreads();
    #pragma unroll
    for (int pi = 0; pi < 6; ++pi)
        #pragma unroll
        for (int ni = 0; ni < 2; ++ni) {
            int d = w * 32 + ni * 16 + (l & 15);
            #pragma unroll
            for (int r = 0; r < 4; ++r) {
                int p = pi * 16 + (l >> 4) * 4 + r;
                C1[p][d] = acc[pi][ni][r] + b1[p];
            }
        }
    __syncthreads();
    #pragma unroll
    for (int i = 0; i < 8; ++i) {
        int oidx = t + i * 256;
        if (oidx < 2016) {
            int p = oidx / 21, q = oidx % 21;
            f32x4 s4 = (f32x4){0.f, 0.f, 0.f, 0.f};
            for (int d4 = 0; d4 < 32; ++d4) {
                f32x4 cv = *(f32x4*)&C1[p][d4 * 4];
                f32x4 wv = *(const f32x4*)(w2 + q * 128 + d4 * 4);
                s4 += cv * wv;
            }
            out[b * 2016 + oidx] = s4[0] + s4[1] + s4[2] + s4[3] + b2[q];
        }
    }
}

extern "C" void kernel_launch(void* const* d_in, const int* in_sizes, int n_in,
                              void* d_out, int out_size, void* d_ws, size_t ws_size,
                              hipStream_t stream) {
    const float* x       = (const float*)d_in[0];
    const float* token_w = (const float*)d_in[1];
    const float* patch_w = (const float*)d_in[2];
    const float* patch_b = (const float*)d_in[3];
    const float* Wi      = (const float*)d_in[4];
    const float* pconv_w = (const float*)d_in[5];
    const float* pconv_b = (const float*)d_in[6];
    const float* bn_g    = (const float*)d_in[7];
    const float* bn_b    = (const float*)d_in[8];
    const float* aconv_w = (const float*)d_in[9];
    const float* fc1_w   = (const float*)d_in[10];
    const float* fc1_b   = (const float*)d_in[11];
    const float* fc2_w   = (const float*)d_in[12];
    const float* fc2_b   = (const float*)d_in[13];
    float* out = (float*)d_out;

    // ---- workspace (floats): total 2,486,144 f = 9.94 MB ----
    float* ws    = (float*)d_ws;
    float* x5    = ws;                                        // 786432
    float* alpha = ws + 786432;                               // 2048
    unsigned short* Wp  = (unsigned short*)(ws + 788480);     // 589824 ush
    unsigned short* w1p = (unsigned short*)(ws + 1083392);    // 36864 ush
    float* twT   = ws + 1101824;                              // 8064
    float* emb   = ws + 1109888;                              // 393216 (dead after k_patch)
    unsigned short* xfT = (unsigned short*)(ws + 1109888);    // 786432 ush (aliases emb)
    unsigned short* XT  = (unsigned short*)(ws + 1503104);    // 917504 ush
    unsigned short* Y0T = (unsigned short*)(ws + 1961856);    // 1048576 ush

    const int thr = 256;
    k_wpack<<<2480, thr, 0, stream>>>(Wi, fc1_w, token_w, Wp, w1p, twT);
    k_zero_halo<<<128, thr, 0, stream>>>(Y0T);
    k_embed<<<1536, thr, 0, stream>>>(x, twT, emb);
    k_patch<<<4096, 192, 0, stream>>>(emb, patch_w, patch_b, x5);
    // layer 0
    k_stats<<<16, thr, 0, stream>>>(x5, pconv_w, pconv_b, bn_g, bn_b, aconv_w, alpha);
    k_xtpack<<<112, thr, 0, stream>>>(x5, XT);
    k_gemm_fwd<<<192, thr, 0, stream>>>(XT, Wp, alpha, Y0T);
    k_gemm_bwd<<<192, thr, 0, stream>>>(Y0T, Wp + 147456, x5, XT, 0);
    // layer 1
    k_stats<<<16, thr, 0, stream>>>(x5, pconv_w + 49152, pconv_b + 128, bn_g + 128,
                                    bn_b + 128, aconv_w + 16384, alpha);
    k_gemm_fwd<<<192, thr, 0, stream>>>(XT, Wp + 2 * 147456, alpha, Y0T);
    k_gemm_bwd<<<192, thr, 0, stream>>>(Y0T, Wp + 3 * 147456, x5, xfT, 1);
    // head
    k_head<<<16, thr, 0, stream>>>(xfT, w1p, fc1_b, fc2_w, fc2_b, out);
}

// Round 7
// 230.135 us; speedup vs baseline: 5.1664x; 1.2714x over previous
//
#include <hip/hip_runtime.h>
#include <math.h>

// ---- static config ----
constexpr int cB = 16, cL = 192, cCIN = 21, cD = 128;
constexpr int cNT = 16, cHW = 24;
constexpr int cPRED = 96, cCOUT = 21;
constexpr int cYH = 14, cYW = 22;

typedef __attribute__((ext_vector_type(8))) short bf16x8;
typedef __attribute__((ext_vector_type(4))) float f32x4;

__device__ inline unsigned short f2bf(float f) {
    union { float f; unsigned u; } v; v.f = f;
    unsigned u = v.u;
    unsigned r = (u + 0x7fffu + ((u >> 16) & 1u)) >> 16;
    return (unsigned short)r;
}

__device__ inline f32x4 mfma16(bf16x8 a, bf16x8 b, f32x4 c) {
    return __builtin_amdgcn_mfma_f32_16x16x32_bf16(a, b, c, 0, 0, 0);
}

// ---------- K0: all one-time packs + tables + Y0T halo zero ----------
// ranges: Wp 589824 | w1p 36864 | twT 8064 | w2p 4096 | w2s 32 | peT 24576 | halo 16384
__global__ void k_init(const float* __restrict__ Wi, const float* __restrict__ fc1_w,
                       const float* __restrict__ token_w, const float* __restrict__ fc2_w,
                       unsigned short* __restrict__ Wp, unsigned short* __restrict__ w1p,
                       float* __restrict__ twT, unsigned short* __restrict__ w2p,
                       float* __restrict__ w2s, float* __restrict__ peT,
                       unsigned short* __restrict__ Y0T) {
    int e = blockIdx.x * blockDim.x + threadIdx.x;
    if (e < 589824) {
        int lyr = e / 294912;
        int rem = e % 294912;
        int dir = rem / 147456;
        int q = rem % 147456;
        int kt = q >> 12;
        int oi = (q >> 9) & 7;
        int kg = (q >> 7) & 3;
        int r  = (q >> 3) & 15;
        int j  = q & 7;
        int k = kt * 32 + kg * 8 + j;
        int a = k >> 7;
        int o, c;
        if (dir == 0) { o = oi * 16 + r; c = k & 127; }
        else          { o = k & 127;     c = oi * 16 + r; }
        Wp[e] = f2bf(Wi[lyr * 147456 + o * 1152 + c * 9 + a]);
        return;
    }
    e -= 589824;
    if (e < 36864) {
        int p = e / 384, mh = e % 384;
        w1p[e] = f2bf(fc1_w[p * 384 + 3 * (mh & 127) + (mh >> 7)]);
        return;
    }
    e -= 36864;
    if (e < 8064) {
        int d = e & 127, c3 = e >> 7;
        twT[e] = token_w[d * 63 + c3];
        return;
    }
    e -= 8064;
    if (e < 4096) {
        int q = e >> 7, d = e & 127;
        w2p[e] = (q < 21) ? f2bf(fc2_w[q * 128 + d]) : (unsigned short)0;
        return;
    }
    e -= 4096;
    if (e < 32) {
        if (e < 21) {
            float s = 0.f;
            for (int d = 0; d < 128; ++d) s += fc2_w[e * 128 + d];
            w2s[e] = s;
        } else if (e < 32) w2s[e] = 0.f;
        return;
    }
    e -= 32;
    if (e < 24576) {
        int l = e >> 7, d = e & 127;
        int i2 = d >> 1;
        float dv = expf(-(float)(2 * i2) * (9.210340371976184f / 128.f));
        float ang = (float)l * dv;
        peT[e] = (d & 1) ? cosf(ang) : sinf(ang);
        return;
    }
    e -= 24576;
    if (e < 16384) {
        int n = e >> 10, j = e & 1023;   // rows 0..63 are the first 8192 ush per n
        bf16x8 z = {0, 0, 0, 0, 0, 0, 0, 0};
        *(bf16x8*)(Y0T + n * 65536 + j * 8) = z;
    }
}

// ---------- K1: token conv (circular) + pos-embed table ----------
__global__ void k_embed(const float* __restrict__ x, const float* __restrict__ twT,
                        const float* __restrict__ peT, float* __restrict__ emb) {
    int idx = blockIdx.x * blockDim.x + threadIdx.x;
    if (idx >= cB * cL * cD) return;
    int d = idx & 127;
    int r = idx >> 7;
    int l = r % cL;
    int b = r / cL;
    int lm = (l == 0) ? 191 : l - 1;
    int lp = (l == 191) ? 0 : l + 1;
    const float* xb = x + b * 4032;
    float acc = peT[l * 128 + d];
    for (int c = 0; c < cCIN; ++c) {
        float x0 = xb[lm * 21 + c], x1 = xb[l * 21 + c], x2 = xb[lp * 21 + c];
        const float* tb = twT + c * 384 + d;
        acc += x0 * tb[0] + x1 * tb[128] + x2 * tb[256];
    }
    emb[idx] = acc;
}

// ---------- K2: patch embed (torch reshape semantics) ----------
__global__ __launch_bounds__(192) void k_patch(const float* __restrict__ emb,
                                               const float* __restrict__ pw,
                                               const float* __restrict__ pb,
                                               float* __restrict__ x5) {
    __shared__ float pwL[24][24];
    int t = threadIdx.x;
    for (int z = t; z < 576; z += 192) pwL[z / 24][z % 24] = pw[z];
    __syncthreads();
    int pair = blockIdx.x * 8 + t / 24;
    int p = t % 24;
    int i = pair >> 4, tt = pair & 15;
    const float* ebase = emb + i * 192;
    int j0 = tt * 12;
    float acc = pb[p];
    #pragma unroll
    for (int k = 0; k < 24; ++k) {
        int j = j0 + k;
        j = j > 191 ? 191 : j;
        acc += ebase[j] * pwL[p][k];
    }
    int G = (i & 127) * 384 + tt * 24 + p;
    int b = i >> 7;
    int tp = G / 3072;
    int pp2 = (G % 3072) / 128;
    int cc = G & 127;
    x5[b * 49152 + cc * 384 + tp * 24 + (pp2 & 1) * 12 + (pp2 >> 1)] = acc;
}

// ---------- K3: fused stats (pool+pconv+BN/relu+tpool+alpha) + optional XT pack ----------
__global__ __launch_bounds__(256) void k_stats(const float* __restrict__ x5,
        const float* __restrict__ pw, const float* __restrict__ pb,
        const float* __restrict__ g, const float* __restrict__ bb,
        const float* __restrict__ aw, float* __restrict__ alpha,
        unsigned short* __restrict__ XT, int pack) {
    __shared__ float ppT[18][128];
    __shared__ float part[256];
    __shared__ float pooled[128];
    __shared__ unsigned short tile[64][136];
    int b = blockIdx.x, t = threadIdx.x;
    if (t < 128) { ppT[0][t] = 0.f; ppT[17][t] = 0.f; }
    #pragma unroll
    for (int i = 0; i < 8; ++i) {
        int ct = t + 256 * i;
        const float* p = x5 + b * 49152 + ct * 24;
        float s = 0.f;
        #pragma unroll
        for (int j = 0; j < 6; ++j) {
            f32x4 v = *(const f32x4*)(p + 4 * j);
            s += v[0] + v[1] + v[2] + v[3];
        }
        ppT[1 + (ct & 15)][ct >> 4] = s * (1.f / 24.f);
    }
    __syncthreads();
    int o = t >> 1, th = (t & 1) * 8;
    float acc[8];
    float pbo = pb[o];
    #pragma unroll
    for (int i = 0; i < 8; ++i) acc[i] = pbo;
    for (int c4 = 0; c4 < 32; ++c4) {
        union { f32x4 v[3]; float f[12]; } u;
        u.v[0] = *(const f32x4*)(pw + o * 384 + c4 * 12);
        u.v[1] = *(const f32x4*)(pw + o * 384 + c4 * 12 + 4);
        u.v[2] = *(const f32x4*)(pw + o * 384 + c4 * 12 + 8);
        f32x4 pv[10];
        #pragma unroll
        for (int r = 0; r < 10; ++r) pv[r] = *(f32x4*)&ppT[th + r][c4 * 4];
        #pragma unroll
        for (int cc = 0; cc < 4; ++cc) {
            float a0 = u.f[cc * 3], a1 = u.f[cc * 3 + 1], a2 = u.f[cc * 3 + 2];
            #pragma unroll
            for (int i = 0; i < 8; ++i)
                acc[i] += a0 * pv[i][cc] + a1 * pv[i + 1][cc] + a2 * pv[i + 2][cc];
        }
    }
    float scale = g[o] * rsqrtf(1.f + 1e-5f);
    float beta = bb[o];
    float partial = 0.f;
    #pragma unroll
    for (int i = 0; i < 8; ++i) {
        float v = acc[i] * scale + beta;
        partial += v > 0.f ? v : 0.f;
    }
    part[t] = partial;
    __syncthreads();
    if (t < 128) pooled[t] = (part[2 * t] + part[2 * t + 1]) * (1.f / 16.f);
    __syncthreads();
    if (t < 128) {
        float a = 1.f;
        for (int c4 = 0; c4 < 32; ++c4) {
            f32x4 av = *(const f32x4*)(aw + t * 128 + c4 * 4);
            f32x4 pv4 = *(f32x4*)&pooled[c4 * 4];
            a += av[0] * pv4[0] + av[1] * pv4[1] + av[2] * pv4[2] + av[3] * pv4[3];
        }
        alpha[b * 128 + t] = a;
    }
    if (!pack) return;
    // ---- pack x5[b] -> XT[b][pp][c] bf16 (rows 384..447 zero) ----
    for (int ch = 0; ch < 6; ++ch) {
        __syncthreads();
        int p4 = (t & 15) * 4;
        #pragma unroll
        for (int i = 0; i < 8; ++i) {
            int c = (t >> 4) + i * 16;
            f32x4 v = *(const f32x4*)(x5 + b * 49152 + c * 384 + ch * 64 + p4);
            #pragma unroll
            for (int r = 0; r < 4; ++r) tile[p4 + r][c] = f2bf(v[r]);
        }
        __syncthreads();
        #pragma unroll
        for (int i = 0; i < 4; ++i) {
            int idx = t + i * 256;
            int pp = idx >> 4, c8 = (idx & 15) * 8;
            *(bf16x8*)(XT + b * 57344 + (ch * 64 + pp) * 128 + c8) = *(bf16x8*)&tile[pp][c8];
        }
    }
    bf16x8 z = {0, 0, 0, 0, 0, 0, 0, 0};
    #pragma unroll
    for (int i = 0; i < 4; ++i) {
        int idx = t + i * 256;
        int pp = idx >> 4, c8 = (idx & 15) * 8;
        *(bf16x8*)(XT + b * 57344 + (384 + pp) * 128 + c8) = z;
    }
}

// ---------- K4: conv-fwd GEMM, 1-wave blocks, no barriers ----------
__global__ __launch_bounds__(64) void k_gfwd(const unsigned short* __restrict__ XT,
        const unsigned short* __restrict__ Wp, const float* __restrict__ alpha,
        unsigned short* __restrict__ Y0T) {
    int bid = blockIdx.x;                 // 384 = 192 rm x 2 cn
    int rm = bid >> 1, cn = bid & 1;
    int n = rm / 12, p0 = (rm % 12) * 32;
    int o0 = cn * 64;
    int l = threadIdx.x;
    int sm = l & 15, skg = l >> 4;
    const unsigned short* XTn = XT + n * 57344;
    const unsigned short* WB = Wp + (o0 >> 4) * 512 + l * 8;
    f32x4 acc[2][4];
    #pragma unroll
    for (int mi = 0; mi < 2; ++mi)
        #pragma unroll
        for (int ni = 0; ni < 4; ++ni) acc[mi][ni] = (f32x4){0.f, 0.f, 0.f, 0.f};
    #pragma unroll
    for (int kt = 0; kt < 36; ++kt) {
        int a = kt >> 2;
        int off = (a / 3) * 24 + (a % 3);
        int kc = (kt & 3) * 32 + skg * 8;
        const unsigned short* ab = XTn + (p0 + sm + off) * 128 + kc;
        bf16x8 a0 = *(const bf16x8*)(ab);
        bf16x8 a1 = *(const bf16x8*)(ab + 2048);
        const unsigned short* wb = WB + kt * 4096;
        bf16x8 b0 = *(const bf16x8*)(wb);
        bf16x8 b1 = *(const bf16x8*)(wb + 512);
        bf16x8 b2 = *(const bf16x8*)(wb + 1024);
        bf16x8 b3 = *(const bf16x8*)(wb + 1536);
        acc[0][0] = mfma16(a0, b0, acc[0][0]);
        acc[0][1] = mfma16(a0, b1, acc[0][1]);
        acc[0][2] = mfma16(a0, b2, acc[0][2]);
        acc[0][3] = mfma16(a0, b3, acc[0][3]);
        acc[1][0] = mfma16(a1, b0, acc[1][0]);
        acc[1][1] = mfma16(a1, b1, acc[1][1]);
        acc[1][2] = mfma16(a1, b2, acc[1][2]);
        acc[1][3] = mfma16(a1, b3, acc[1][3]);
    }
    #pragma unroll
    for (int ni = 0; ni < 4; ++ni) {
        int o = o0 + ni * 16 + sm;
        float s = 0.f;
        #pragma unroll
        for (int bb2 = 0; bb2 < 16; ++bb2) { float a = alpha[bb2 * 128 + o]; s += a * a; }
        #pragma unroll
        for (int mi = 0; mi < 2; ++mi) {
            #pragma unroll
            for (int r = 0; r < 4; ++r) {
                int p = p0 + mi * 16 + skg * 4 + r;
                bool valid = ((p % 24) < cYW) && ((p / 24) < cYH);
                float v = valid ? acc[mi][ni][r] * s : 0.f;
                Y0T[n * 65536 + (64 + p) * 128 + o] = f2bf(v);
            }
        }
    }
}

// ---------- K5: conv-bwd GEMM + residual RMW; emits XT (mode0) or xfM (mode1) ----------
__global__ __launch_bounds__(64) void k_gbwd(const unsigned short* __restrict__ Y0T,
        const unsigned short* __restrict__ Wpb, float* __restrict__ x5,
        unsigned short* __restrict__ xdst, int mode) {
    __shared__ unsigned short tr[32][72];
    int bid = blockIdx.x;                 // 384
    int rm = bid >> 1, cn = bid & 1;
    int n = rm / 12, p0 = (rm % 12) * 32;
    int c0 = cn * 64;
    int l = threadIdx.x;
    int sm = l & 15, skg = l >> 4;
    const unsigned short* Yn = Y0T + n * 65536 + 64 * 128;
    const unsigned short* WB = Wpb + (c0 >> 4) * 512 + l * 8;
    f32x4 acc[2][4];
    #pragma unroll
    for (int mi = 0; mi < 2; ++mi)
        #pragma unroll
        for (int ni = 0; ni < 4; ++ni) acc[mi][ni] = (f32x4){0.f, 0.f, 0.f, 0.f};
    #pragma unroll
    for (int kt = 0; kt < 36; ++kt) {
        int a = kt >> 2;
        int off = (a / 3) * 24 + (a % 3);
        int kc = (kt & 3) * 32 + skg * 8;
        const unsigned short* ab = Yn + (p0 + sm - off) * 128 + kc;
        bf16x8 a0 = *(const bf16x8*)(ab);
        bf16x8 a1 = *(const bf16x8*)(ab + 2048);
        const unsigned short* wb = WB + kt * 4096;
        bf16x8 b0 = *(const bf16x8*)(wb);
        bf16x8 b1 = *(const bf16x8*)(wb + 512);
        bf16x8 b2 = *(const bf16x8*)(wb + 1024);
        bf16x8 b3 = *(const bf16x8*)(wb + 1536);
        acc[0][0] = mfma16(a0, b0, acc[0][0]);
        acc[0][1] = mfma16(a0, b1, acc[0][1]);
        acc[0][2] = mfma16(a0, b2, acc[0][2]);
        acc[0][3] = mfma16(a0, b3, acc[0][3]);
        acc[1][0] = mfma16(a1, b0, acc[1][0]);
        acc[1][1] = mfma16(a1, b1, acc[1][1]);
        acc[1][2] = mfma16(a1, b2, acc[1][2]);
        acc[1][3] = mfma16(a1, b3, acc[1][3]);
    }
    #pragma unroll
    for (int ni = 0; ni < 4; ++ni) {
        int cl = ni * 16 + sm;
        int c = c0 + cl;
        #pragma unroll
        for (int mi = 0; mi < 2; ++mi) {
            int pl = mi * 16 + skg * 4;
            float* dst = x5 + n * 49152 + c * 384 + p0 + pl;
            f32x4 ov = *(f32x4*)dst;
            #pragma unroll
            for (int r = 0; r < 4; ++r) {
                ov[r] += acc[mi][ni][r];
                tr[pl + r][cl] = f2bf(ov[r]);
            }
            *(f32x4*)dst = ov;
        }
    }
    __syncthreads();
    if (mode == 0) {
        #pragma unroll
        for (int pass = 0; pass < 4; ++pass) {
            int idx = pass * 64 + l;
            int row = idx >> 3, ch = idx & 7;
            *(bf16x8*)(xdst + n * 57344 + (p0 + row) * 128 + c0 + ch * 8) = *(bf16x8*)&tr[row][ch * 8];
        }
    } else {
        #pragma unroll
        for (int pass = 0; pass < 4; ++pass) {
            int idx = pass * 64 + l;
            int cl = idx >> 2, pl0 = (idx & 3) * 8;
            __attribute__((aligned(16))) unsigned short tmp[8];
            #pragma unroll
            for (int j2 = 0; j2 < 8; ++j2) tmp[j2] = tr[pl0 + j2][cl];
            *(bf16x8*)(xdst + n * 49152 + ((p0 >> 7) * 128 + c0 + cl) * 128 + (p0 & 127) + pl0) =
                *(bf16x8*)tmp;
        }
    }
}

// ---------- K6: Zt[b][q][mh] = sum_d xfM[b][mh][d] * w2p[q][d] ----------
__global__ __launch_bounds__(64) void k_gemmZ(const unsigned short* __restrict__ xfM,
        const unsigned short* __restrict__ w2p, unsigned short* __restrict__ Zt) {
    int bid = blockIdx.x;                 // 192
    int b = bid / 12, m0 = (bid % 12) * 32;
    int l = threadIdx.x, sm = l & 15, skg = l >> 4;
    f32x4 acc[2][2];
    #pragma unroll
    for (int mi = 0; mi < 2; ++mi)
        #pragma unroll
        for (int ni = 0; ni < 2; ++ni) acc[mi][ni] = (f32x4){0.f, 0.f, 0.f, 0.f};
    #pragma unroll
    for (int kt = 0; kt < 4; ++kt) {
        int kc = kt * 32 + skg * 8;
        const unsigned short* ab = xfM + b * 49152 + (m0 + sm) * 128 + kc;
        bf16x8 a0 = *(const bf16x8*)(ab);
        bf16x8 a1 = *(const bf16x8*)(ab + 2048);
        bf16x8 b0 = *(const bf16x8*)(w2p + sm * 128 + kc);
        bf16x8 b1 = *(const bf16x8*)(w2p + (16 + sm) * 128 + kc);
        acc[0][0] = mfma16(a0, b0, acc[0][0]);
        acc[0][1] = mfma16(a0, b1, acc[0][1]);
        acc[1][0] = mfma16(a1, b0, acc[1][0]);
        acc[1][1] = mfma16(a1, b1, acc[1][1]);
    }
    #pragma unroll
    for (int mi = 0; mi < 2; ++mi)
        #pragma unroll
        for (int ni = 0; ni < 2; ++ni) {
            int q = ni * 16 + sm;
            int mh = m0 + mi * 16 + skg * 4;
            #pragma unroll
            for (int r = 0; r < 4; ++r)
                Zt[b * 12288 + q * 384 + mh + r] = f2bf(acc[mi][ni][r]);
        }
}

// ---------- K7: out[b][p][q] = sum_mh w1p[p][mh]*Zt[b][q][mh] + b1[p]*w2s[q] + b2[q] ----------
__global__ __launch_bounds__(64) void k_gemmO(const unsigned short* __restrict__ w1p,
        const unsigned short* __restrict__ Zt, const float* __restrict__ b1,
        const float* __restrict__ w2s, const float* __restrict__ b2,
        float* __restrict__ out) {
    int bid = blockIdx.x;                 // 48
    int b = bid / 3, p0 = (bid % 3) * 32;
    int l = threadIdx.x, sm = l & 15, skg = l >> 4;
    f32x4 acc[2][2];
    #pragma unroll
    for (int mi = 0; mi < 2; ++mi)
        #pragma unroll
        for (int ni = 0; ni < 2; ++ni) acc[mi][ni] = (f32x4){0.f, 0.f, 0.f, 0.f};
    #pragma unroll
    for (int kt = 0; kt < 12; ++kt) {
        int kc = kt * 32 + skg * 8;
        const unsigned short* ab = w1p + (p0 + sm) * 384 + kc;
        bf16x8 a0 = *(const bf16x8*)(ab);
        bf16x8 a1 = *(const bf16x8*)(ab + 16 * 384);
        const unsigned short* zb = Zt + b * 12288 + sm * 384 + kc;
        bf16x8 b0 = *(const bf16x8*)(zb);
        bf16x8 b1v = *(const bf16x8*)(zb + 16 * 384);
        acc[0][0] = mfma16(a0, b0, acc[0][0]);
        acc[0][1] = mfma16(a0, b1v, acc[0][1]);
        acc[1][0] = mfma16(a1, b0, acc[1][0]);
        acc[1][1] = mfma16(a1, b1v, acc[1][1]);
    }
    #pragma unroll
    for (int ni = 0; ni < 2; ++ni) {
        int q = ni * 16 + sm;
        if (q < 21) {
            float wsq = w2s[q], bq = b2[q];
            #pragma unroll
            for (int mi = 0; mi < 2; ++mi) {
                #pragma unroll
                for (int r = 0; r < 4; ++r) {
                    int p = p0 + mi * 16 + skg * 4 + r;
                    out[b * 2016 + p * 21 + q] = acc[mi][ni][r] + b1[p] * wsq + bq;
                }
            }
        }
    }
}

extern "C" void kernel_launch(void* const* d_in, const int* in_sizes, int n_in,
                              void* d_out, int out_size, void* d_ws, size_t ws_size,
                              hipStream_t stream) {
    const float* x       = (const float*)d_in[0];
    const float* token_w = (const float*)d_in[1];
    const float* patch_w = (const float*)d_in[2];
    const float* patch_b = (const float*)d_in[3];
    const float* Wi      = (const float*)d_in[4];
    const float* pconv_w = (const float*)d_in[5];
    const float* pconv_b = (const float*)d_in[6];
    const float* bn_g    = (const float*)d_in[7];
    const float* bn_b    = (const float*)d_in[8];
    const float* aconv_w = (const float*)d_in[9];
    const float* fc1_w   = (const float*)d_in[10];
    const float* fc1_b   = (const float*)d_in[11];
    const float* fc2_w   = (const float*)d_in[12];
    const float* fc2_b   = (const float*)d_in[13];
    float* out = (float*)d_out;

    // ---- workspace (floats), total 2,119,584 f = 8.48 MB ----
    float* ws    = (float*)d_ws;
    float* x5    = ws;                                        // 786432
    float* alpha = ws + 786432;                               // 2048
    unsigned short* Wp  = (unsigned short*)(ws + 788480);     // 589824 ush
    unsigned short* w1p = (unsigned short*)(ws + 1083392);    // 36864 ush
    unsigned short* w2p = (unsigned short*)(ws + 1101824);    // 4096 ush
    float* w2s   = ws + 1103872;                              // 32
    float* twT   = ws + 1103904;                              // 8064
    float* peT   = ws + 1111968;                              // 24576
    float* emb   = ws + 1136544;                              // 393216 (dead after k_patch)
    unsigned short* XT  = (unsigned short*)(ws + 1136544 + 393216); // 917504 ush
    unsigned short* xfM = XT;                                 // alias (used after XT dead)
    unsigned short* Y0T = (unsigned short*)(ws + 1136544 + 393216 + 458752); // 1048576 ush
    unsigned short* Zt  = Y0T;                                // alias (used after Y0T dead)

    k_init<<<2656, 256, 0, stream>>>(Wi, fc1_w, token_w, fc2_w, Wp, w1p, twT, w2p, w2s, peT, Y0T);
    k_embed<<<1536, 256, 0, stream>>>(x, twT, peT, emb);
    k_patch<<<4096, 192, 0, stream>>>(emb, patch_w, patch_b, x5);
    // layer 0
    k_stats<<<16, 256, 0, stream>>>(x5, pconv_w, pconv_b, bn_g, bn_b, aconv_w, alpha, XT, 1);
    k_gfwd<<<384, 64, 0, stream>>>(XT, Wp, alpha, Y0T);
    k_gbwd<<<384, 64, 0, stream>>>(Y0T, Wp + 147456, x5, XT, 0);
    // layer 1
    k_stats<<<16, 256, 0, stream>>>(x5, pconv_w + 49152, pconv_b + 128, bn_g + 128,
                                    bn_b + 128, aconv_w + 16384, alpha, XT, 0);
    k_gfwd<<<384, 64, 0, stream>>>(XT, Wp + 2 * 147456, alpha, Y0T);
    k_gbwd<<<384, 64, 0, stream>>>(Y0T, Wp + 3 * 147456, x5, xfM, 1);
    // head
    k_gemmZ<<<192, 64, 0, stream>>>(xfM, w2p, Zt);
    k_gemmO<<<48, 64, 0, stream>>>(w1p, Zt, fc1_b, w2s, fc2_b, out);
}